// Round 15
// baseline (430.647 us; speedup 1.0000x reference)
//
#include <hip/hip_runtime.h>
#include <hip/hip_bf16.h>
#include <cstdint>

typedef __hip_bfloat16 bf16;
#define CDIV(a,b) (((a)+(b)-1)/(b))

typedef __attribute__((ext_vector_type(8))) short short8;
typedef __attribute__((ext_vector_type(8))) unsigned short usht8;
typedef __attribute__((ext_vector_type(4))) float f32x4v;
typedef __attribute__((ext_vector_type(2))) float f32x2;
typedef __attribute__((ext_vector_type(2))) int i32x2;

struct us4 { unsigned short x, y, z, w; };

// ---------------- device helpers ----------------
__device__ __forceinline__ float lrelu02(float x) { return fmaxf(x, 0.f) + 0.2f * fminf(x, 0.f); }

__device__ __forceinline__ float b2f(unsigned short u) {
    return __uint_as_float((unsigned)u << 16);
}
__device__ __forceinline__ unsigned short f2b(float f) {
    unsigned u = __float_as_uint(f);
    unsigned r = u + 0x7FFFu + ((u >> 16) & 1u);
    return (unsigned short)(r >> 16);
}
__device__ __forceinline__ f32x2 vabs2(f32x2 x) {
    i32x2 u = __builtin_bit_cast(i32x2, x) & (i32x2)0x7fffffff;
    return __builtin_bit_cast(f32x2, u);
}
// swizzled LDS index (ushort units) for [row][32] tiles, 8-elem granularity
__device__ __forceinline__ int swz(int row, int kg) {
    return row * 32 + (kg ^ ((row >> 1) & 3)) * 8;
}

// ---------------- fill ----------------
__global__ void fill_i32(int* __restrict__ p, int v, long n) {
    long i = (long)blockIdx.x * blockDim.x + threadIdx.x;
    long st = (long)gridDim.x * blockDim.x;
    for (; i < n; i += st) p[i] = v;
}

// ---------------- CSR build (both directions fused) ----------------
__global__ void hist2_kernel(const int* __restrict__ edm, const int* __restrict__ edu,
                             int* __restrict__ deg_m, int* __restrict__ deg_u, int E) {
    int e = blockIdx.x * blockDim.x + threadIdx.x;
    if (e < E) atomicAdd(&deg_m[edm[e]], 1);
    else if (e < 2 * E) atomicAdd(&deg_u[edu[e - E]], 1);
}

#define SCAN_T 256
#define SCAN_E 16
__global__ void __launch_bounds__(SCAN_T) scan1_dual_kernel(
    const int* __restrict__ deg0, int* __restrict__ off0, int* __restrict__ bsum0, int n0,
    const int* __restrict__ deg1, int* __restrict__ off1, int* __restrict__ bsum1, int n1)
{
    const int* deg = blockIdx.y ? deg1 : deg0;
    int* off  = blockIdx.y ? off1 : off0;
    int* bsum = blockIdx.y ? bsum1 : bsum0;
    const int n = blockIdx.y ? n1 : n0;

    __shared__ int lds[SCAN_T];
    const int tb = blockIdx.x * (SCAN_T * SCAN_E) + threadIdx.x * SCAN_E;
    int v[SCAN_E];
    int tot = 0;
#pragma unroll
    for (int j = 0; j < SCAN_E; ++j) {
        v[j] = (tb + j < n) ? deg[tb + j] : 0;
        tot += v[j];
    }
    lds[threadIdx.x] = tot;
    __syncthreads();
    for (int s = 1; s < SCAN_T; s <<= 1) {
        int t = (threadIdx.x >= s) ? lds[threadIdx.x - s] : 0;
        __syncthreads();
        lds[threadIdx.x] += t;
        __syncthreads();
    }
    int run = (threadIdx.x > 0) ? lds[threadIdx.x - 1] : 0;
#pragma unroll
    for (int j = 0; j < SCAN_E; ++j) {
        if (tb + j < n) off[tb + j] = run;
        run += v[j];
    }
    if (threadIdx.x == SCAN_T - 1) bsum[blockIdx.x] = lds[SCAN_T - 1];
}
__global__ void scan2_dual_kernel(int* __restrict__ bm, int nbm, int* __restrict__ bu, int nbu) {
    int t = threadIdx.x & 63;
    int* b = (threadIdx.x >= 64) ? bu : bm;
    int nb = (threadIdx.x >= 64) ? nbu : nbm;
    int orig = (t < nb) ? b[t] : 0;
    int v = orig;
    for (int s = 1; s < 64; s <<= 1) {
        int u = __shfl_up(v, s);
        if (t >= s) v += u;
    }
    if (t < nb) b[t] = v - orig;
}
__global__ void scan3_dual_kernel(int* __restrict__ off0, const int* __restrict__ bsum0, int n0,
                                  int* __restrict__ off1, const int* __restrict__ bsum1, int n1) {
    int* off = blockIdx.y ? off1 : off0;
    const int* bsum = blockIdx.y ? bsum1 : bsum0;
    const int n = blockIdx.y ? n1 : n0;
    int i = blockIdx.x * blockDim.x + threadIdx.x;
    if (i < n) off[i] += bsum[i / (SCAN_T * SCAN_E)];
}

__global__ void csr_fill2_kernel(
    const int* __restrict__ esm, const int* __restrict__ edm, const float* __restrict__ eam,
    const int* __restrict__ offm, int* __restrict__ curm, int2* __restrict__ recm,
    const int* __restrict__ esu, const int* __restrict__ edu, const float* __restrict__ eau,
    const int* __restrict__ offu, int* __restrict__ curu, int2* __restrict__ recu, int E)
{
    int e = blockIdx.x * blockDim.x + threadIdx.x;
    if (e < E) {
        int d = edm[e];
        int r = atomicAdd(&curm[d], 1);
        int2 q; q.x = esm[e]; q.y = __float_as_int(eam[e]);
        recm[offm[d] + r] = q;
    } else if (e < 2 * E) {
        e -= E;
        int d = edu[e];
        int r = atomicAdd(&curu[d], 1);
        int2 q; q.x = esu[e]; q.y = __float_as_int(eau[e]);
        recu[offu[d] + r] = q;
    }
}

// ---------------- weight transpose+convert ----------------
struct TxArgs {
    const float* src[4];
    unsigned short* dst[4];
};
__global__ void txp_kernel(TxArgs a) {
    const int m = blockIdx.y;
    const int K = 256, N = 256;
    const long total = (long)K * N;
    const float* __restrict__ s = a.src[m];
    unsigned short* __restrict__ d = a.dst[m];
    for (long i = (long)blockIdx.x * blockDim.x + threadIdx.x; i < total;
         i += (long)gridDim.x * blockDim.x) {
        int k = (int)(i >> 8), nn = (int)(i & 255);
        d[(long)nn * K + k] = f2b(s[i]);
    }
}

// ---------------- combine phase-0 + layer-0 weights ----------
__global__ void cw_kernel(const float* __restrict__ Wu, const float* __restrict__ bu,
                          const float* __restrict__ Wa, const float* __restrict__ ba,
                          const float* __restrict__ Wb, const float* __restrict__ bb,
                          unsigned short* __restrict__ wt, float* __restrict__ bc)
{
    int tid = blockIdx.x * blockDim.x + threadIdx.x;
    if (tid < 512 * 64) {
        int nn = tid >> 6, k = tid & 63;
        const float* Ws = (nn < 256) ? Wa : Wb;
        int nc = nn & 255;
        float s = 0.f;
        for (int c = 0; c < 64; ++c) s = fmaf(Wu[k * 64 + c], Ws[c * 256 + nc], s);
        wt[nn * 64 + k] = f2b(s);
    } else if (tid < 512 * 64 + 512) {
        int nn = tid - 512 * 64;
        const float* Ws = (nn < 256) ? Wa : Wb;
        const float* bs = (nn < 256) ? ba : bb;
        int nc = nn & 255;
        float s = bs[nc];
        for (int c = 0; c < 64; ++c) s = fmaf(bu[c], Ws[c * 256 + nc], s);
        bc[nn] = s;
    }
}

// ---------------- merged MFMA GEMM, BK=32 (two independent segments) ------
struct GemmP {
    const void* A; const int* ids;
    const unsigned short* Wt0; const unsigned short* Wt1;
    const float* b0; const float* b1;
    unsigned short* Y0; unsigned short* Y1;
    int n;
};
template<int K, bool GATHER>
__global__ void __launch_bounds__(256) gemm2_kernel(GemmP P0, GemmP P1, int nblk0)
{
    const bool seg1 = (int)blockIdx.x >= nblk0;
    const GemmP P = seg1 ? P1 : P0;
    const int lb = seg1 ? (int)blockIdx.x - nblk0 : (int)blockIdx.x;

    const int t = threadIdx.x;
    const int wid = t >> 6, lane = t & 63;
    const int half = lb & 1;
    const int row0 = (lb >> 1) * 64;
    const unsigned short* Wt = half ? P.Wt1 : P.Wt0;
    const float* bias = half ? P.b1 : P.b0;
    unsigned short* Y = half ? P.Y1 : P.Y0;
    const int n = P.n;

    __shared__ unsigned short SMEM[64 * 32 + 256 * 32];   // As | Ws; reused as C-stage
    unsigned short* As = SMEM;
    unsigned short* Ws = SMEM + 64 * 32;

    f32x4v acc[4][4];
#pragma unroll
    for (int rt = 0; rt < 4; ++rt)
#pragma unroll
        for (int ct = 0; ct < 4; ++ct) acc[rt][ct] = (f32x4v){0.f, 0.f, 0.f, 0.f};

    const int r_st = t >> 2, kg_st = t & 3;
    const int grow = row0 + r_st;
    long abase = 0;
    if (grow < n) abase = GATHER ? (long)P.ids[grow] * K : (long)grow * K;

    for (int kt = 0; kt < K / 32; ++kt) {
        usht8 av = (usht8)0;
        if (grow < n) {
            if (GATHER) {
                const float* p = (const float*)P.A + abase + kt * 32 + kg_st * 8;
#pragma unroll
                for (int j = 0; j < 8; ++j) av[j] = f2b(p[j]);
            } else {
                av = *(const usht8*)((const unsigned short*)P.A + abase + kt * 32 + kg_st * 8);
            }
        }
        *(usht8*)&As[swz(r_st, kg_st)] = av;
#pragma unroll
        for (int i = 0; i < 4; ++i) {
            int idx = t + i * 256;
            int c = idx >> 2, kg = idx & 3;
            *(usht8*)&Ws[swz(c, kg)] = *(const usht8*)&Wt[(long)c * K + kt * 32 + kg * 8];
        }
        __syncthreads();

        const int kgrp = lane >> 4;
        short8 af[4];
#pragma unroll
        for (int rt = 0; rt < 4; ++rt)
            af[rt] = *(const short8*)&As[swz(rt * 16 + (lane & 15), kgrp)];
#pragma unroll
        for (int ct = 0; ct < 4; ++ct) {
            int col = wid * 64 + ct * 16 + (lane & 15);
            short8 bfr = *(const short8*)&Ws[swz(col, kgrp)];
#pragma unroll
            for (int rt = 0; rt < 4; ++rt)
                acc[rt][ct] = __builtin_amdgcn_mfma_f32_16x16x32_bf16(af[rt], bfr, acc[rt][ct], 0, 0, 0);
        }
        __syncthreads();
    }

    // ---- epilogue: stage bf16 C tile in LDS, store dense 16B chunks ----
    float bb[4];
#pragma unroll
    for (int ct = 0; ct < 4; ++ct) bb[ct] = bias[wid * 64 + ct * 16 + (lane & 15)];

#pragma unroll
    for (int rh = 0; rh < 2; ++rh) {
#pragma unroll
        for (int rt = rh * 2; rt < rh * 2 + 2; ++rt) {
#pragma unroll
            for (int ct = 0; ct < 4; ++ct) {
                int col = wid * 64 + ct * 16 + (lane & 15);
#pragma unroll
                for (int j = 0; j < 4; ++j) {
                    int rl = rt * 16 + (lane >> 4) * 4 + j - rh * 32;
                    SMEM[rl * 256 + col] = f2b(acc[rt][ct][j] + bb[ct]);
                }
            }
        }
        __syncthreads();
#pragma unroll
        for (int i = 0; i < 4; ++i) {
            int idx = t + i * 256;
            int rl = idx >> 5, cseg = (idx & 31) * 8;
            int row = row0 + rh * 32 + rl;
            if (row < n)
                *(usht8*)&Y[(long)row * 256 + cseg] = *(const usht8*)&SMEM[rl * 256 + cseg];
        }
        __syncthreads();
    }
}

// ---------------- merged fused GATv2 layer (two independent segments) -----
// lane = h*16 + q; lane owns channels c = h*64 + q*4 .. +3. One wave per dst.
// 4-edge batches; packed-f32 (v_pk_*) channel math; exp2-domain defer-max
// softmax; u32 gather addressing.
// NOTE: segments' read/write buffer sets MUST be disjoint (no launch-internal order).
struct GatP {
    const int* deg; const int* off; const int2* rec;
    const unsigned short* xl; const unsigned short* xr;
    const float* We; const float* att; const float* bias;
    const float* g; const float* be;
    void* y;
    int n;
};
template<bool CONCAT>
__global__ void __launch_bounds__(256) gat2_kernel(GatP P0, GatP P1, int nblk0)
{
    const bool seg1 = (int)blockIdx.x >= nblk0;
    const GatP P = seg1 ? P1 : P0;
    const int lb = seg1 ? (int)blockIdx.x - nblk0 : (int)blockIdx.x;
    const int lane = threadIdx.x & 63;
    const int d = lb * 4 + (threadIdx.x >> 6);
    if (d >= P.n) return;

    const int q = lane & 15;
    const int c0 = ((lane >> 4) << 6) + (q << 2);   // h*64 + q*4
    const unsigned cb = (unsigned)c0 << 1;          // byte offset of lane's channels
    const float LOG2E = 1.4426950408889634f;

    // ---- per-wave constants (logits in log2 domain, packed f32x2) ----
    float4 We4 = *(const float4*)(P.We + c0);
    float4 att4 = *(const float4*)(P.att + c0);
    f32x2 We2[2] = { {We4.x, We4.y}, {We4.z, We4.w} };
    f32x2 a06[2] = { {0.6f * LOG2E * att4.x, 0.6f * LOG2E * att4.y},
                     {0.6f * LOG2E * att4.z, 0.6f * LOG2E * att4.w} };
    f32x2 a04[2] = { {0.4f * LOG2E * att4.x, 0.4f * LOG2E * att4.y},
                     {0.4f * LOG2E * att4.z, 0.4f * LOG2E * att4.w} };
    const int ec = CONCAT ? c0 : (q << 2);
    float4 bi = *(const float4*)(P.bias + ec);
    float4 gg = *(const float4*)(P.g + ec);
    float4 bb = *(const float4*)(P.be + ec);

    us4 xrv = *(const us4*)(P.xr + (long)d * 256 + c0);
    f32x2 xr2[2] = { {b2f(xrv.x), b2f(xrv.y)}, {b2f(xrv.z), b2f(xrv.w)} };

    float m = -1e30f, den = 0.f;
    f32x2 acc2[2] = { (f32x2)0.f, (f32x2)0.f };

    const int dg = P.deg[d], o0 = P.off[d];
    const char* __restrict__ xlb = (const char*)P.xl;

    for (int base = 0; base < dg; base += 64) {
        int2 r;
        if (base + lane < dg) r = P.rec[o0 + base + lane];
        else { r.x = 0; r.y = 0; }
        const int cnt = min(dg - base, 64);
        for (int j = 0; j < cnt; j += 4) {
            us4 xvA[4];
            int aB[4];
#pragma unroll
            for (int u = 0; u < 4; ++u) {
                int s = __builtin_amdgcn_readlane(r.x, j + u);   // SGPR broadcast
                aB[u] = __builtin_amdgcn_readlane(r.y, j + u);
                xvA[u] = *(const us4*)(xlb + (((unsigned)s << 9) + cb));
            }
            float l[4];
            f32x2 xv2[4][2];
#pragma unroll
            for (int u = 0; u < 4; ++u) {
                xv2[u][0] = (f32x2){b2f(xvA[u].x), b2f(xvA[u].y)};
                xv2[u][1] = (f32x2){b2f(xvA[u].z), b2f(xvA[u].w)};
                const float a = __int_as_float(aB[u]);
                f32x2 t0 = xv2[u][0] + (a * We2[0] + xr2[0]);    // v_pk_fma chains
                f32x2 t1 = xv2[u][1] + (a * We2[1] + xr2[1]);
                f32x2 p2 = a06[0] * t0 + a04[0] * vabs2(t0);
                p2 = p2 + a06[1] * t1 + a04[1] * vabs2(t1);
                float part = p2.x + p2.y;
#pragma unroll
                for (int st = 1; st < 16; st <<= 1) part += __shfl_xor(part, st);
                l[u] = (j + u < cnt) ? part : -1e30f;
            }
            // defer-max rescale (exact): p bounded by 2^11.54 = e^8
            float bmax = fmaxf(fmaxf(l[0], l[1]), fmaxf(l[2], l[3]));
            if (__any(bmax > m + 11.5415603f)) {
                float mn = fmaxf(m, bmax);
                float sc = exp2f(m - mn);
                den *= sc;
                acc2[0] *= sc;
                acc2[1] *= sc;
                m = mn;
            }
#pragma unroll
            for (int u = 0; u < 4; ++u) {
                float p = exp2f(l[u] - m);
                den += p;
                acc2[0] += p * xv2[u][0];
                acc2[1] += p * xv2[u][1];
            }
        }
    }

    float accs[4] = {acc2[0].x, acc2[0].y, acc2[1].x, acc2[1].y};
    const float id = 1.f / (den + 1e-16f);
    if (CONCAT) {
        float v[4], s1 = 0.f, s2 = 0.f;
#pragma unroll
        for (int i = 0; i < 4; ++i) {
            v[i] = fmaf(accs[i], id, (&bi.x)[i]);
            s1 += v[i]; s2 = fmaf(v[i], v[i], s2);
        }
#pragma unroll
        for (int st = 1; st < 64; st <<= 1) {
            s1 += __shfl_xor(s1, st);
            s2 += __shfl_xor(s2, st);
        }
        float mean = s1 * (1.f / 256.f);
        float var = s2 * (1.f / 256.f) - mean * mean;
        float rr = rsqrtf(var + 1e-5f);
        us4 o;
        o.x = f2b(lrelu02(fmaf((&gg.x)[0] * rr, v[0] - mean, (&bb.x)[0])));
        o.y = f2b(lrelu02(fmaf((&gg.x)[1] * rr, v[1] - mean, (&bb.x)[1])));
        o.z = f2b(lrelu02(fmaf((&gg.x)[2] * rr, v[2] - mean, (&bb.x)[2])));
        o.w = f2b(lrelu02(fmaf((&gg.x)[3] * rr, v[3] - mean, (&bb.x)[3])));
        *(us4*)((unsigned short*)P.y + (long)d * 256 + c0) = o;
    } else {
        float vh[4];
#pragma unroll
        for (int i = 0; i < 4; ++i) vh[i] = accs[i] * id;
#pragma unroll
        for (int st = 16; st < 64; st <<= 1)
#pragma unroll
            for (int i = 0; i < 4; ++i) vh[i] += __shfl_xor(vh[i], st);
        float v[4], s1 = 0.f, s2 = 0.f;
#pragma unroll
        for (int i = 0; i < 4; ++i) {
            v[i] = fmaf(0.25f, vh[i], (&bi.x)[i]);
            s1 += v[i]; s2 = fmaf(v[i], v[i], s2);
        }
#pragma unroll
        for (int st = 1; st < 16; st <<= 1) {
            s1 += __shfl_xor(s1, st);
            s2 += __shfl_xor(s2, st);
        }
        float mean = s1 * (1.f / 64.f);
        float var = s2 * (1.f / 64.f) - mean * mean;
        float rr = rsqrtf(var + 1e-5f);
        if (lane < 16) {
            float4 o;
            o.x = lrelu02(fmaf((&gg.x)[0] * rr, v[0] - mean, (&bb.x)[0]));
            o.y = lrelu02(fmaf((&gg.x)[1] * rr, v[1] - mean, (&bb.x)[1]));
            o.z = lrelu02(fmaf((&gg.x)[2] * rr, v[2] - mean, (&bb.x)[2]));
            o.w = lrelu02(fmaf((&gg.x)[3] * rr, v[3] - mean, (&bb.x)[3]));
            *(float4*)((float*)P.y + (long)d * 64 + (q << 2)) = o;
        }
    }
}

// ---------------- host orchestration ----------------
extern "C" void kernel_launch(void* const* d_in, const int* in_sizes, int n_in,
                              void* d_out, int out_size, void* d_ws, size_t ws_size,
                              hipStream_t stream)
{
    auto F = [&](int i) { return (const float*)d_in[i]; };
    auto I = [&](int i) { return (const int*)d_in[i]; };

    const int NU = in_sizes[0];
    const int NM = in_sizes[1];
    const int E  = in_sizes[2] / 2;

    const int* user_ids  = I(0);
    const int* movie_ids = I(1);
    const int* ei_um = I(2);
    const int* ei_mu = I(3);
    const float* ea_um = F(4);
    const float* ea_mu = F(5);
    const float* user_emb  = F(6);
    const float* movie_emb = F(7);
    const float* W_user = F(8),  *b_user = F(9);
    const float* W_movie = F(10), *b_movie = F(11);
    const int L0UM = 12, L0MU = 19, L1UM = 26, L1MU = 33;
    const float* g0u = F(40), *be0u = F(41);
    const float* g0m = F(42), *be0m = F(43);
    const float* g1u = F(44), *be1u = F(45);
    const float* g1m = F(46), *be1m = F(47);

    // ---- workspace layout ----
    char* w = (char*)d_ws;
    size_t off = 0;
    auto alloc = [&](size_t bytes) -> void* {
        void* p = w + off;
        off = (off + bytes + 255) & ~(size_t)255;
        return p;
    };
    bf16* UB1 = (bf16*)alloc((size_t)NU * 256 * 2);
    bf16* UB2 = (bf16*)alloc((size_t)NU * 256 * 2);
    bf16* UB3 = (bf16*)alloc((size_t)NU * 256 * 2);
    bf16* MB1 = (bf16*)alloc((size_t)NM * 256 * 2);
    bf16* MB2 = (bf16*)alloc((size_t)NM * 256 * 2);
    bf16* MB3 = (bf16*)alloc((size_t)NM * 256 * 2);
    int* degcur = (int*)alloc((size_t)2 * (NM + NU) * 4);
    int* deg_m = degcur;
    int* deg_u = degcur + NM;
    int* cur_m = degcur + NM + NU;
    int* cur_u = degcur + 2 * NM + NU;
    int* off_m = (int*)alloc((size_t)NM * 4);
    int* off_u = (int*)alloc((size_t)NU * 4);
    int2* rec_m = (int2*)alloc((size_t)(E + 8) * 8);
    int2* rec_u = (int2*)alloc((size_t)(E + 8) * 8);
    int* bsum_m = (int*)alloc(64 * 4);
    int* bsum_u = (int*)alloc(64 * 4);
    unsigned short* wt_l1um_l = (unsigned short*)alloc(256 * 256 * 2);
    unsigned short* wt_l1mu_r = (unsigned short*)alloc(256 * 256 * 2);
    unsigned short* wt_l1um_r = (unsigned short*)alloc(256 * 256 * 2);
    unsigned short* wt_l1mu_l = (unsigned short*)alloc(256 * 256 * 2);
    unsigned short* wt_c_user  = (unsigned short*)alloc(512 * 64 * 2);
    unsigned short* wt_c_movie = (unsigned short*)alloc(512 * 64 * 2);
    float* bc_user  = (float*)alloc(512 * 4);
    float* bc_movie = (float*)alloc(512 * 4);
    if (off > ws_size) return;

    float* out_u = (float*)d_out;
    float* out_m = out_u + (size_t)NU * 64;

    const int FB = 256;

    // ---- weight prep ----
    TxArgs tx;
    tx.src[0] = F(L1UM+0); tx.dst[0] = wt_l1um_l;
    tx.src[1] = F(L1MU+2); tx.dst[1] = wt_l1mu_r;
    tx.src[2] = F(L1UM+2); tx.dst[2] = wt_l1um_r;
    tx.src[3] = F(L1MU+0); tx.dst[3] = wt_l1mu_l;
    txp_kernel<<<dim3(64, 4), 256, 0, stream>>>(tx);
    cw_kernel<<<CDIV(512 * 64 + 512, 256), 256, 0, stream>>>(
        W_user, b_user, F(L0UM+0), F(L0UM+1), F(L0MU+2), F(L0MU+3), wt_c_user, bc_user);
    cw_kernel<<<CDIV(512 * 64 + 512, 256), 256, 0, stream>>>(
        W_movie, b_movie, F(L0UM+2), F(L0UM+3), F(L0MU+0), F(L0MU+1), wt_c_movie, bc_movie);

    // ---- CSR build (both directions) ----
    fill_i32<<<CDIV(2 * (NM + NU), FB), FB, 0, stream>>>(degcur, 0, (long)2 * (NM + NU));
    hist2_kernel<<<CDIV(2 * E, FB), FB, 0, stream>>>(ei_um + E, ei_mu + E, deg_m, deg_u, E);
    const int nbm = CDIV(NM, SCAN_T * SCAN_E), nbu = CDIV(NU, SCAN_T * SCAN_E);
    scan1_dual_kernel<<<dim3(max(nbm, nbu), 2), SCAN_T, 0, stream>>>(
        deg_m, off_m, bsum_m, NM, deg_u, off_u, bsum_u, NU);
    scan2_dual_kernel<<<1, 128, 0, stream>>>(bsum_m, nbm, bsum_u, nbu);
    scan3_dual_kernel<<<dim3(CDIV(max(NM, NU), FB), 2), FB, 0, stream>>>(
        off_m, bsum_m, NM, off_u, bsum_u, NU);
    csr_fill2_kernel<<<CDIV(2 * E, FB), FB, 0, stream>>>(
        ei_um, ei_um + E, ea_um, off_m, cur_m, rec_m,
        ei_mu, ei_mu + E, ea_mu, off_u, cur_u, rec_u, E);

    // ---- layer-0 projections (merged movie+user; phase-0 folded, K=64) ----
    {
        GemmP PM{movie_emb, movie_ids, wt_c_movie, wt_c_movie + 256 * 64,
                 bc_movie, bc_movie + 256, (unsigned short*)MB1, (unsigned short*)MB3, NM};
        GemmP PU{user_emb, user_ids, wt_c_user, wt_c_user + 256 * 64,
                 bc_user, bc_user + 256, (unsigned short*)UB1, (unsigned short*)UB2, NU};
        int nM = CDIV(NM, 64) * 2, nU = CDIV(NU, 64) * 2;
        gemm2_kernel<64, true><<<nM + nU, 256, 0, stream>>>(PM, PU, nM);
        // MB1=xr_m0, MB3=xl_m0, UB1=xl_u0, UB2=xr_u0
    }

    // ---- layer 0 fused GAT (merged; writes {MB2, UB3} disjoint from reads) ----
    {
        GatP PM{deg_m, off_m, rec_m, (const unsigned short*)UB1, (const unsigned short*)MB1,
                F(L0UM+4), F(L0UM+5), F(L0UM+6), g0m, be0m, MB2, NM};          // xm1
        GatP PU{deg_u, off_u, rec_u, (const unsigned short*)MB3, (const unsigned short*)UB2,
                F(L0MU+4), F(L0MU+5), F(L0MU+6), g0u, be0u, UB3, NU};          // xu1 -> UB3
        gat2_kernel<true><<<CDIV(NM, 4) + CDIV(NU, 4), 256, 0, stream>>>(PM, PU, CDIV(NM, 4));
    }

    // ---- layer-1 projections (merged; reads {MB2,UB3}, writes {MB1,MB3,UB1,UB2}) ----
    {
        GemmP PM{(unsigned short*)MB2, nullptr, wt_l1um_r, wt_l1mu_l,
                 F(L1UM+3), F(L1MU+1), (unsigned short*)MB1, (unsigned short*)MB3, NM};
        GemmP PU{(unsigned short*)UB3, nullptr, wt_l1um_l, wt_l1mu_r,
                 F(L1UM+1), F(L1MU+3), (unsigned short*)UB1, (unsigned short*)UB2, NU};
        int nM = CDIV(NM, 64) * 2, nU = CDIV(NU, 64) * 2;
        gemm2_kernel<256, false><<<nM + nU, 256, 0, stream>>>(PM, PU, nM);
        // MB1=xr_m1, MB3=xl_m1, UB1=xl_u1, UB2=xr_u1
    }

    // ---- layer 1 fused GAT (merged; reads {UB1,MB1,MB3,UB2}, writes d_out) ----
    {
        GatP PM{deg_m, off_m, rec_m, (const unsigned short*)UB1, (const unsigned short*)MB1,
                F(L1UM+4), F(L1UM+5), F(L1UM+6), g1m, be1m, out_m, NM};
        GatP PU{deg_u, off_u, rec_u, (const unsigned short*)MB3, (const unsigned short*)UB2,
                F(L1MU+4), F(L1MU+5), F(L1MU+6), g1u, be1u, out_u, NU};
        gat2_kernel<false><<<CDIV(NM, 4) + CDIV(NU, 4), 256, 0, stream>>>(PM, PU, CDIV(NM, 4));
    }
}

// Round 16
// 397.383 us; speedup vs baseline: 1.0837x; 1.0837x over previous
//
#include <hip/hip_runtime.h>
#include <hip/hip_bf16.h>
#include <cstdint>

typedef __hip_bfloat16 bf16;
#define CDIV(a,b) (((a)+(b)-1)/(b))

typedef __attribute__((ext_vector_type(8))) short short8;
typedef __attribute__((ext_vector_type(8))) unsigned short usht8;
typedef __attribute__((ext_vector_type(4))) float f32x4v;

struct us4 { unsigned short x, y, z, w; };

// ---------------- device helpers ----------------
__device__ __forceinline__ float lrelu02(float x) { return fmaxf(x, 0.f) + 0.2f * fminf(x, 0.f); }

__device__ __forceinline__ float b2f(unsigned short u) {
    return __uint_as_float((unsigned)u << 16);
}
__device__ __forceinline__ unsigned short f2b(float f) {
    unsigned u = __float_as_uint(f);
    unsigned r = u + 0x7FFFu + ((u >> 16) & 1u);
    return (unsigned short)(r >> 16);
}
// swizzled LDS index (ushort units) for [row][32] tiles, 8-elem granularity
__device__ __forceinline__ int swz(int row, int kg) {
    return row * 32 + (kg ^ ((row >> 1) & 3)) * 8;
}

// ---------------- fill ----------------
__global__ void fill_i32(int* __restrict__ p, int v, long n) {
    long i = (long)blockIdx.x * blockDim.x + threadIdx.x;
    long st = (long)gridDim.x * blockDim.x;
    for (; i < n; i += st) p[i] = v;
}

// ---------------- CSR build (both directions fused) ----------------
__global__ void hist2_kernel(const int* __restrict__ edm, const int* __restrict__ edu,
                             int* __restrict__ deg_m, int* __restrict__ deg_u, int E) {
    int e = blockIdx.x * blockDim.x + threadIdx.x;
    if (e < E) atomicAdd(&deg_m[edm[e]], 1);
    else if (e < 2 * E) atomicAdd(&deg_u[edu[e - E]], 1);
}

#define SCAN_T 256
#define SCAN_E 16
__global__ void __launch_bounds__(SCAN_T) scan1_dual_kernel(
    const int* __restrict__ deg0, int* __restrict__ off0, int* __restrict__ bsum0, int n0,
    const int* __restrict__ deg1, int* __restrict__ off1, int* __restrict__ bsum1, int n1)
{
    const int* deg = blockIdx.y ? deg1 : deg0;
    int* off  = blockIdx.y ? off1 : off0;
    int* bsum = blockIdx.y ? bsum1 : bsum0;
    const int n = blockIdx.y ? n1 : n0;

    __shared__ int lds[SCAN_T];
    const int tb = blockIdx.x * (SCAN_T * SCAN_E) + threadIdx.x * SCAN_E;
    int v[SCAN_E];
    int tot = 0;
#pragma unroll
    for (int j = 0; j < SCAN_E; ++j) {
        v[j] = (tb + j < n) ? deg[tb + j] : 0;
        tot += v[j];
    }
    lds[threadIdx.x] = tot;
    __syncthreads();
    for (int s = 1; s < SCAN_T; s <<= 1) {
        int t = (threadIdx.x >= s) ? lds[threadIdx.x - s] : 0;
        __syncthreads();
        lds[threadIdx.x] += t;
        __syncthreads();
    }
    int run = (threadIdx.x > 0) ? lds[threadIdx.x - 1] : 0;
#pragma unroll
    for (int j = 0; j < SCAN_E; ++j) {
        if (tb + j < n) off[tb + j] = run;
        run += v[j];
    }
    if (threadIdx.x == SCAN_T - 1) bsum[blockIdx.x] = lds[SCAN_T - 1];
}
__global__ void scan2_dual_kernel(int* __restrict__ bm, int nbm, int* __restrict__ bu, int nbu) {
    int t = threadIdx.x & 63;
    int* b = (threadIdx.x >= 64) ? bu : bm;
    int nb = (threadIdx.x >= 64) ? nbu : nbm;
    int orig = (t < nb) ? b[t] : 0;
    int v = orig;
    for (int s = 1; s < 64; s <<= 1) {
        int u = __shfl_up(v, s);
        if (t >= s) v += u;
    }
    if (t < nb) b[t] = v - orig;
}
__global__ void scan3_dual_kernel(int* __restrict__ off0, const int* __restrict__ bsum0, int n0,
                                  int* __restrict__ off1, const int* __restrict__ bsum1, int n1) {
    int* off = blockIdx.y ? off1 : off0;
    const int* bsum = blockIdx.y ? bsum1 : bsum0;
    const int n = blockIdx.y ? n1 : n0;
    int i = blockIdx.x * blockDim.x + threadIdx.x;
    if (i < n) off[i] += bsum[i / (SCAN_T * SCAN_E)];
}

__global__ void csr_fill2_kernel(
    const int* __restrict__ esm, const int* __restrict__ edm, const float* __restrict__ eam,
    const int* __restrict__ offm, int* __restrict__ curm, int2* __restrict__ recm,
    const int* __restrict__ esu, const int* __restrict__ edu, const float* __restrict__ eau,
    const int* __restrict__ offu, int* __restrict__ curu, int2* __restrict__ recu, int E)
{
    int e = blockIdx.x * blockDim.x + threadIdx.x;
    if (e < E) {
        int d = edm[e];
        int r = atomicAdd(&curm[d], 1);
        int2 q; q.x = esm[e]; q.y = __float_as_int(eam[e]);
        recm[offm[d] + r] = q;
    } else if (e < 2 * E) {
        e -= E;
        int d = edu[e];
        int r = atomicAdd(&curu[d], 1);
        int2 q; q.x = esu[e]; q.y = __float_as_int(eau[e]);
        recu[offu[d] + r] = q;
    }
}

// ---------------- weight transpose+convert ----------------
struct TxArgs {
    const float* src[4];
    unsigned short* dst[4];
};
__global__ void txp_kernel(TxArgs a) {
    const int m = blockIdx.y;
    const int K = 256, N = 256;
    const long total = (long)K * N;
    const float* __restrict__ s = a.src[m];
    unsigned short* __restrict__ d = a.dst[m];
    for (long i = (long)blockIdx.x * blockDim.x + threadIdx.x; i < total;
         i += (long)gridDim.x * blockDim.x) {
        int k = (int)(i >> 8), nn = (int)(i & 255);
        d[(long)nn * K + k] = f2b(s[i]);
    }
}

// ---------------- combine phase-0 + layer-0 weights ----------
__global__ void cw_kernel(const float* __restrict__ Wu, const float* __restrict__ bu,
                          const float* __restrict__ Wa, const float* __restrict__ ba,
                          const float* __restrict__ Wb, const float* __restrict__ bb,
                          unsigned short* __restrict__ wt, float* __restrict__ bc)
{
    int tid = blockIdx.x * blockDim.x + threadIdx.x;
    if (tid < 512 * 64) {
        int nn = tid >> 6, k = tid & 63;
        const float* Ws = (nn < 256) ? Wa : Wb;
        int nc = nn & 255;
        float s = 0.f;
        for (int c = 0; c < 64; ++c) s = fmaf(Wu[k * 64 + c], Ws[c * 256 + nc], s);
        wt[nn * 64 + k] = f2b(s);
    } else if (tid < 512 * 64 + 512) {
        int nn = tid - 512 * 64;
        const float* Ws = (nn < 256) ? Wa : Wb;
        const float* bs = (nn < 256) ? ba : bb;
        int nc = nn & 255;
        float s = bs[nc];
        for (int c = 0; c < 64; ++c) s = fmaf(bu[c], Ws[c * 256 + nc], s);
        bc[nn] = s;
    }
}

// ---------------- merged MFMA GEMM, BK=32 (two independent segments) ------
struct GemmP {
    const void* A; const int* ids;
    const unsigned short* Wt0; const unsigned short* Wt1;
    const float* b0; const float* b1;
    unsigned short* Y0; unsigned short* Y1;
    int n;
};
template<int K, bool GATHER>
__global__ void __launch_bounds__(256) gemm2_kernel(GemmP P0, GemmP P1, int nblk0)
{
    const bool seg1 = (int)blockIdx.x >= nblk0;
    const GemmP P = seg1 ? P1 : P0;
    const int lb = seg1 ? (int)blockIdx.x - nblk0 : (int)blockIdx.x;

    const int t = threadIdx.x;
    const int wid = t >> 6, lane = t & 63;
    const int half = lb & 1;
    const int row0 = (lb >> 1) * 64;
    const unsigned short* Wt = half ? P.Wt1 : P.Wt0;
    const float* bias = half ? P.b1 : P.b0;
    unsigned short* Y = half ? P.Y1 : P.Y0;
    const int n = P.n;

    __shared__ unsigned short SMEM[64 * 32 + 256 * 32];   // As | Ws; reused as C-stage
    unsigned short* As = SMEM;
    unsigned short* Ws = SMEM + 64 * 32;

    f32x4v acc[4][4];
#pragma unroll
    for (int rt = 0; rt < 4; ++rt)
#pragma unroll
        for (int ct = 0; ct < 4; ++ct) acc[rt][ct] = (f32x4v){0.f, 0.f, 0.f, 0.f};

    const int r_st = t >> 2, kg_st = t & 3;
    const int grow = row0 + r_st;
    long abase = 0;
    if (grow < n) abase = GATHER ? (long)P.ids[grow] * K : (long)grow * K;

    for (int kt = 0; kt < K / 32; ++kt) {
        usht8 av = (usht8)0;
        if (grow < n) {
            if (GATHER) {
                const float* p = (const float*)P.A + abase + kt * 32 + kg_st * 8;
#pragma unroll
                for (int j = 0; j < 8; ++j) av[j] = f2b(p[j]);
            } else {
                av = *(const usht8*)((const unsigned short*)P.A + abase + kt * 32 + kg_st * 8);
            }
        }
        *(usht8*)&As[swz(r_st, kg_st)] = av;
#pragma unroll
        for (int i = 0; i < 4; ++i) {
            int idx = t + i * 256;
            int c = idx >> 2, kg = idx & 3;
            *(usht8*)&Ws[swz(c, kg)] = *(const usht8*)&Wt[(long)c * K + kt * 32 + kg * 8];
        }
        __syncthreads();

        const int kgrp = lane >> 4;
        short8 af[4];
#pragma unroll
        for (int rt = 0; rt < 4; ++rt)
            af[rt] = *(const short8*)&As[swz(rt * 16 + (lane & 15), kgrp)];
#pragma unroll
        for (int ct = 0; ct < 4; ++ct) {
            int col = wid * 64 + ct * 16 + (lane & 15);
            short8 bfr = *(const short8*)&Ws[swz(col, kgrp)];
#pragma unroll
            for (int rt = 0; rt < 4; ++rt)
                acc[rt][ct] = __builtin_amdgcn_mfma_f32_16x16x32_bf16(af[rt], bfr, acc[rt][ct], 0, 0, 0);
        }
        __syncthreads();
    }

    // ---- epilogue: stage bf16 C tile in LDS, store dense 16B chunks ----
    float bb[4];
#pragma unroll
    for (int ct = 0; ct < 4; ++ct) bb[ct] = bias[wid * 64 + ct * 16 + (lane & 15)];

#pragma unroll
    for (int rh = 0; rh < 2; ++rh) {
#pragma unroll
        for (int rt = rh * 2; rt < rh * 2 + 2; ++rt) {
#pragma unroll
            for (int ct = 0; ct < 4; ++ct) {
                int col = wid * 64 + ct * 16 + (lane & 15);
#pragma unroll
                for (int j = 0; j < 4; ++j) {
                    int rl = rt * 16 + (lane >> 4) * 4 + j - rh * 32;
                    SMEM[rl * 256 + col] = f2b(acc[rt][ct][j] + bb[ct]);
                }
            }
        }
        __syncthreads();
#pragma unroll
        for (int i = 0; i < 4; ++i) {
            int idx = t + i * 256;
            int rl = idx >> 5, cseg = (idx & 31) * 8;
            int row = row0 + rh * 32 + rl;
            if (row < n)
                *(usht8*)&Y[(long)row * 256 + cseg] = *(const usht8*)&SMEM[rl * 256 + cseg];
        }
        __syncthreads();
    }
}

// ---------------- merged fused GATv2 layer (two independent segments) -----
// lane = h*16 + q; lane owns channels c = h*64 + q*4 .. +3. One wave per dst
// (per-dst blocks -> HW backfills wave slots). 4-edge batches; scalar f32
// math (proven fastest: 44 VGPR / 46% occupancy); exp2-domain defer-max
// softmax; u32 gather addressing.
// NOTE: segments' read/write buffer sets MUST be disjoint (no launch-internal order).
struct GatP {
    const int* deg; const int* off; const int2* rec;
    const unsigned short* xl; const unsigned short* xr;
    const float* We; const float* att; const float* bias;
    const float* g; const float* be;
    void* y;
    int n;
};
template<bool CONCAT>
__global__ void __launch_bounds__(256) gat2_kernel(GatP P0, GatP P1, int nblk0)
{
    const bool seg1 = (int)blockIdx.x >= nblk0;
    const GatP P = seg1 ? P1 : P0;
    const int lb = seg1 ? (int)blockIdx.x - nblk0 : (int)blockIdx.x;
    const int lane = threadIdx.x & 63;
    const int d = lb * 4 + (threadIdx.x >> 6);
    if (d >= P.n) return;

    const int q = lane & 15;
    const int c0 = ((lane >> 4) << 6) + (q << 2);   // h*64 + q*4
    const unsigned cb = (unsigned)c0 << 1;          // byte offset of lane's channels
    const float LOG2E = 1.4426950408889634f;

    // ---- per-wave constants (logits carried in log2 domain) ----
    float4 We4 = *(const float4*)(P.We + c0);
    float4 att4 = *(const float4*)(P.att + c0);
    float att06[4], att04[4];
#pragma unroll
    for (int i = 0; i < 4; ++i) {
        att06[i] = 0.6f * LOG2E * (&att4.x)[i];
        att04[i] = 0.4f * LOG2E * (&att4.x)[i];
    }
    const int ec = CONCAT ? c0 : (q << 2);
    float4 bi = *(const float4*)(P.bias + ec);
    float4 gg = *(const float4*)(P.g + ec);
    float4 bb = *(const float4*)(P.be + ec);

    us4 xrv = *(const us4*)(P.xr + (long)d * 256 + c0);
    float xr4[4] = {b2f(xrv.x), b2f(xrv.y), b2f(xrv.z), b2f(xrv.w)};

    float m = -1e30f, den = 0.f;
    float acc[4] = {0.f, 0.f, 0.f, 0.f};

    const int dg = P.deg[d], o0 = P.off[d];
    const char* __restrict__ xlb = (const char*)P.xl;

    for (int base = 0; base < dg; base += 64) {
        int2 r;
        if (base + lane < dg) r = P.rec[o0 + base + lane];
        else { r.x = 0; r.y = 0; }
        const int cnt = min(dg - base, 64);
        for (int j = 0; j < cnt; j += 4) {
            us4 xvA[4];
            int aB[4];
#pragma unroll
            for (int u = 0; u < 4; ++u) {
                int s = __builtin_amdgcn_readlane(r.x, j + u);   // SGPR broadcast
                aB[u] = __builtin_amdgcn_readlane(r.y, j + u);
                xvA[u] = *(const us4*)(xlb + (((unsigned)s << 9) + cb));
            }
            float l[4], xvf[4][4];
#pragma unroll
            for (int u = 0; u < 4; ++u) {
                xvf[u][0] = b2f(xvA[u].x); xvf[u][1] = b2f(xvA[u].y);
                xvf[u][2] = b2f(xvA[u].z); xvf[u][3] = b2f(xvA[u].w);
                const float a = __int_as_float(aB[u]);
                float part = 0.f;
#pragma unroll
                for (int i = 0; i < 4; ++i) {
                    float t = xvf[u][i] + fmaf(a, (&We4.x)[i], xr4[i]);
                    part = fmaf(att06[i], t, part);          // log2e*lrelu*att
                    part = fmaf(att04[i], fabsf(t), part);
                }
#pragma unroll
                for (int st = 1; st < 16; st <<= 1) part += __shfl_xor(part, st);
                l[u] = (j + u < cnt) ? part : -1e30f;
            }
            // defer-max rescale (exact): p bounded by 2^11.54 = e^8
            float bmax = fmaxf(fmaxf(l[0], l[1]), fmaxf(l[2], l[3]));
            if (__any(bmax > m + 11.5415603f)) {
                float mn = fmaxf(m, bmax);
                float sc = exp2f(m - mn);
                den *= sc;
#pragma unroll
                for (int i = 0; i < 4; ++i) acc[i] *= sc;
                m = mn;
            }
#pragma unroll
            for (int u = 0; u < 4; ++u) {
                float p = exp2f(l[u] - m);
                den += p;
#pragma unroll
                for (int i = 0; i < 4; ++i) acc[i] = fmaf(p, xvf[u][i], acc[i]);
            }
        }
    }

    const float id = 1.f / (den + 1e-16f);
    if (CONCAT) {
        float v[4], s1 = 0.f, s2 = 0.f;
#pragma unroll
        for (int i = 0; i < 4; ++i) {
            v[i] = fmaf(acc[i], id, (&bi.x)[i]);
            s1 += v[i]; s2 = fmaf(v[i], v[i], s2);
        }
#pragma unroll
        for (int st = 1; st < 64; st <<= 1) {
            s1 += __shfl_xor(s1, st);
            s2 += __shfl_xor(s2, st);
        }
        float mean = s1 * (1.f / 256.f);
        float var = s2 * (1.f / 256.f) - mean * mean;
        float rr = rsqrtf(var + 1e-5f);
        us4 o;
        o.x = f2b(lrelu02(fmaf((&gg.x)[0] * rr, v[0] - mean, (&bb.x)[0])));
        o.y = f2b(lrelu02(fmaf((&gg.x)[1] * rr, v[1] - mean, (&bb.x)[1])));
        o.z = f2b(lrelu02(fmaf((&gg.x)[2] * rr, v[2] - mean, (&bb.x)[2])));
        o.w = f2b(lrelu02(fmaf((&gg.x)[3] * rr, v[3] - mean, (&bb.x)[3])));
        *(us4*)((unsigned short*)P.y + (long)d * 256 + c0) = o;
    } else {
        float vh[4];
#pragma unroll
        for (int i = 0; i < 4; ++i) vh[i] = acc[i] * id;
#pragma unroll
        for (int st = 16; st < 64; st <<= 1)
#pragma unroll
            for (int i = 0; i < 4; ++i) vh[i] += __shfl_xor(vh[i], st);
        float v[4], s1 = 0.f, s2 = 0.f;
#pragma unroll
        for (int i = 0; i < 4; ++i) {
            v[i] = fmaf(0.25f, vh[i], (&bi.x)[i]);
            s1 += v[i]; s2 = fmaf(v[i], v[i], s2);
        }
#pragma unroll
        for (int st = 1; st < 16; st <<= 1) {
            s1 += __shfl_xor(s1, st);
            s2 += __shfl_xor(s2, st);
        }
        float mean = s1 * (1.f / 64.f);
        float var = s2 * (1.f / 64.f) - mean * mean;
        float rr = rsqrtf(var + 1e-5f);
        if (lane < 16) {
            float4 o;
            o.x = lrelu02(fmaf((&gg.x)[0] * rr, v[0] - mean, (&bb.x)[0]));
            o.y = lrelu02(fmaf((&gg.x)[1] * rr, v[1] - mean, (&bb.x)[1]));
            o.z = lrelu02(fmaf((&gg.x)[2] * rr, v[2] - mean, (&bb.x)[2]));
            o.w = lrelu02(fmaf((&gg.x)[3] * rr, v[3] - mean, (&bb.x)[3]));
            *(float4*)((float*)P.y + (long)d * 64 + (q << 2)) = o;
        }
    }
}

// ---------------- host orchestration ----------------
extern "C" void kernel_launch(void* const* d_in, const int* in_sizes, int n_in,
                              void* d_out, int out_size, void* d_ws, size_t ws_size,
                              hipStream_t stream)
{
    auto F = [&](int i) { return (const float*)d_in[i]; };
    auto I = [&](int i) { return (const int*)d_in[i]; };

    const int NU = in_sizes[0];
    const int NM = in_sizes[1];
    const int E  = in_sizes[2] / 2;

    const int* user_ids  = I(0);
    const int* movie_ids = I(1);
    const int* ei_um = I(2);
    const int* ei_mu = I(3);
    const float* ea_um = F(4);
    const float* ea_mu = F(5);
    const float* user_emb  = F(6);
    const float* movie_emb = F(7);
    const float* W_user = F(8),  *b_user = F(9);
    const float* W_movie = F(10), *b_movie = F(11);
    const int L0UM = 12, L0MU = 19, L1UM = 26, L1MU = 33;
    const float* g0u = F(40), *be0u = F(41);
    const float* g0m = F(42), *be0m = F(43);
    const float* g1u = F(44), *be1u = F(45);
    const float* g1m = F(46), *be1m = F(47);

    // ---- workspace layout ----
    char* w = (char*)d_ws;
    size_t off = 0;
    auto alloc = [&](size_t bytes) -> void* {
        void* p = w + off;
        off = (off + bytes + 255) & ~(size_t)255;
        return p;
    };
    bf16* UB1 = (bf16*)alloc((size_t)NU * 256 * 2);
    bf16* UB2 = (bf16*)alloc((size_t)NU * 256 * 2);
    bf16* UB3 = (bf16*)alloc((size_t)NU * 256 * 2);
    bf16* MB1 = (bf16*)alloc((size_t)NM * 256 * 2);
    bf16* MB2 = (bf16*)alloc((size_t)NM * 256 * 2);
    bf16* MB3 = (bf16*)alloc((size_t)NM * 256 * 2);
    int* degcur = (int*)alloc((size_t)2 * (NM + NU) * 4);
    int* deg_m = degcur;
    int* deg_u = degcur + NM;
    int* cur_m = degcur + NM + NU;
    int* cur_u = degcur + 2 * NM + NU;
    int* off_m = (int*)alloc((size_t)NM * 4);
    int* off_u = (int*)alloc((size_t)NU * 4);
    int2* rec_m = (int2*)alloc((size_t)(E + 8) * 8);
    int2* rec_u = (int2*)alloc((size_t)(E + 8) * 8);
    int* bsum_m = (int*)alloc(64 * 4);
    int* bsum_u = (int*)alloc(64 * 4);
    unsigned short* wt_l1um_l = (unsigned short*)alloc(256 * 256 * 2);
    unsigned short* wt_l1mu_r = (unsigned short*)alloc(256 * 256 * 2);
    unsigned short* wt_l1um_r = (unsigned short*)alloc(256 * 256 * 2);
    unsigned short* wt_l1mu_l = (unsigned short*)alloc(256 * 256 * 2);
    unsigned short* wt_c_user  = (unsigned short*)alloc(512 * 64 * 2);
    unsigned short* wt_c_movie = (unsigned short*)alloc(512 * 64 * 2);
    float* bc_user  = (float*)alloc(512 * 4);
    float* bc_movie = (float*)alloc(512 * 4);
    if (off > ws_size) return;

    float* out_u = (float*)d_out;
    float* out_m = out_u + (size_t)NU * 64;

    const int FB = 256;

    // ---- weight prep ----
    TxArgs tx;
    tx.src[0] = F(L1UM+0); tx.dst[0] = wt_l1um_l;
    tx.src[1] = F(L1MU+2); tx.dst[1] = wt_l1mu_r;
    tx.src[2] = F(L1UM+2); tx.dst[2] = wt_l1um_r;
    tx.src[3] = F(L1MU+0); tx.dst[3] = wt_l1mu_l;
    txp_kernel<<<dim3(64, 4), 256, 0, stream>>>(tx);
    cw_kernel<<<CDIV(512 * 64 + 512, 256), 256, 0, stream>>>(
        W_user, b_user, F(L0UM+0), F(L0UM+1), F(L0MU+2), F(L0MU+3), wt_c_user, bc_user);
    cw_kernel<<<CDIV(512 * 64 + 512, 256), 256, 0, stream>>>(
        W_movie, b_movie, F(L0UM+2), F(L0UM+3), F(L0MU+0), F(L0MU+1), wt_c_movie, bc_movie);

    // ---- CSR build (both directions) ----
    fill_i32<<<CDIV(2 * (NM + NU), FB), FB, 0, stream>>>(degcur, 0, (long)2 * (NM + NU));
    hist2_kernel<<<CDIV(2 * E, FB), FB, 0, stream>>>(ei_um + E, ei_mu + E, deg_m, deg_u, E);
    const int nbm = CDIV(NM, SCAN_T * SCAN_E), nbu = CDIV(NU, SCAN_T * SCAN_E);
    scan1_dual_kernel<<<dim3(max(nbm, nbu), 2), SCAN_T, 0, stream>>>(
        deg_m, off_m, bsum_m, NM, deg_u, off_u, bsum_u, NU);
    scan2_dual_kernel<<<1, 128, 0, stream>>>(bsum_m, nbm, bsum_u, nbu);
    scan3_dual_kernel<<<dim3(CDIV(max(NM, NU), FB), 2), FB, 0, stream>>>(
        off_m, bsum_m, NM, off_u, bsum_u, NU);
    csr_fill2_kernel<<<CDIV(2 * E, FB), FB, 0, stream>>>(
        ei_um, ei_um + E, ea_um, off_m, cur_m, rec_m,
        ei_mu, ei_mu + E, ea_mu, off_u, cur_u, rec_u, E);

    // ---- layer-0 projections (merged movie+user; phase-0 folded, K=64) ----
    {
        GemmP PM{movie_emb, movie_ids, wt_c_movie, wt_c_movie + 256 * 64,
                 bc_movie, bc_movie + 256, (unsigned short*)MB1, (unsigned short*)MB3, NM};
        GemmP PU{user_emb, user_ids, wt_c_user, wt_c_user + 256 * 64,
                 bc_user, bc_user + 256, (unsigned short*)UB1, (unsigned short*)UB2, NU};
        int nM = CDIV(NM, 64) * 2, nU = CDIV(NU, 64) * 2;
        gemm2_kernel<64, true><<<nM + nU, 256, 0, stream>>>(PM, PU, nM);
        // MB1=xr_m0, MB3=xl_m0, UB1=xl_u0, UB2=xr_u0
    }

    // ---- layer 0 fused GAT (merged; writes {MB2, UB3} disjoint from reads) ----
    {
        GatP PM{deg_m, off_m, rec_m, (const unsigned short*)UB1, (const unsigned short*)MB1,
                F(L0UM+4), F(L0UM+5), F(L0UM+6), g0m, be0m, MB2, NM};          // xm1
        GatP PU{deg_u, off_u, rec_u, (const unsigned short*)MB3, (const unsigned short*)UB2,
                F(L0MU+4), F(L0MU+5), F(L0MU+6), g0u, be0u, UB3, NU};          // xu1 -> UB3
        gat2_kernel<true><<<CDIV(NM, 4) + CDIV(NU, 4), 256, 0, stream>>>(PM, PU, CDIV(NM, 4));
    }

    // ---- layer-1 projections (merged; reads {MB2,UB3}, writes {MB1,MB3,UB1,UB2}) ----
    {
        GemmP PM{(unsigned short*)MB2, nullptr, wt_l1um_r, wt_l1mu_l,
                 F(L1UM+3), F(L1MU+1), (unsigned short*)MB1, (unsigned short*)MB3, NM};
        GemmP PU{(unsigned short*)UB3, nullptr, wt_l1um_l, wt_l1mu_r,
                 F(L1UM+1), F(L1MU+3), (unsigned short*)UB1, (unsigned short*)UB2, NU};
        int nM = CDIV(NM, 64) * 2, nU = CDIV(NU, 64) * 2;
        gemm2_kernel<256, false><<<nM + nU, 256, 0, stream>>>(PM, PU, nM);
        // MB1=xr_m1, MB3=xl_m1, UB1=xl_u1, UB2=xr_u1
    }

    // ---- layer 1 fused GAT (merged; reads {UB1,MB1,MB3,UB2}, writes d_out) ----
    {
        GatP PM{deg_m, off_m, rec_m, (const unsigned short*)UB1, (const unsigned short*)MB1,
                F(L1UM+4), F(L1UM+5), F(L1UM+6), g1m, be1m, out_m, NM};
        GatP PU{deg_u, off_u, rec_u, (const unsigned short*)MB3, (const unsigned short*)UB2,
                F(L1MU+4), F(L1MU+5), F(L1MU+6), g1u, be1u, out_u, NU};
        gat2_kernel<false><<<CDIV(NM, 4) + CDIV(NU, 4), 256, 0, stream>>>(PM, PU, CDIV(NM, 4));
    }
}

// Round 17
// 393.868 us; speedup vs baseline: 1.0934x; 1.0089x over previous
//
#include <hip/hip_runtime.h>
#include <hip/hip_bf16.h>
#include <cstdint>

typedef __hip_bfloat16 bf16;
#define CDIV(a,b) (((a)+(b)-1)/(b))

typedef __attribute__((ext_vector_type(8))) short short8;
typedef __attribute__((ext_vector_type(8))) unsigned short usht8;
typedef __attribute__((ext_vector_type(4))) float f32x4v;

struct us4 { unsigned short x, y, z, w; };

// ---------------- device helpers ----------------
__device__ __forceinline__ float lrelu02(float x) { return fmaxf(x, 0.f) + 0.2f * fminf(x, 0.f); }

__device__ __forceinline__ float b2f(unsigned short u) {
    return __uint_as_float((unsigned)u << 16);
}
__device__ __forceinline__ unsigned short f2b(float f) {
    unsigned u = __float_as_uint(f);
    unsigned r = u + 0x7FFFu + ((u >> 16) & 1u);
    return (unsigned short)(r >> 16);
}
// swizzled LDS index (ushort units) for [row][32] tiles, 8-elem granularity
__device__ __forceinline__ int swz(int row, int kg) {
    return row * 32 + (kg ^ ((row >> 1) & 3)) * 8;
}
// async global->LDS, 16B per lane; LDS dest = uniform base + lane*16 (m104)
__device__ __forceinline__ void gload16(const void* g, void* l) {
    __builtin_amdgcn_global_load_lds(
        (const __attribute__((address_space(1))) unsigned*)g,
        (__attribute__((address_space(3))) unsigned*)l, 16, 0, 0);
}

// ---------------- fill ----------------
__global__ void fill_i32(int* __restrict__ p, int v, long n) {
    long i = (long)blockIdx.x * blockDim.x + threadIdx.x;
    long st = (long)gridDim.x * blockDim.x;
    for (; i < n; i += st) p[i] = v;
}

// ---------------- CSR build (both directions fused) ----------------
__global__ void hist2_kernel(const int* __restrict__ edm, const int* __restrict__ edu,
                             int* __restrict__ deg_m, int* __restrict__ deg_u, int E) {
    int e = blockIdx.x * blockDim.x + threadIdx.x;
    if (e < E) atomicAdd(&deg_m[edm[e]], 1);
    else if (e < 2 * E) atomicAdd(&deg_u[edu[e - E]], 1);
}

#define SCAN_T 256
#define SCAN_E 16
__global__ void __launch_bounds__(SCAN_T) scan1_dual_kernel(
    const int* __restrict__ deg0, int* __restrict__ off0, int* __restrict__ bsum0, int n0,
    const int* __restrict__ deg1, int* __restrict__ off1, int* __restrict__ bsum1, int n1)
{
    const int* deg = blockIdx.y ? deg1 : deg0;
    int* off  = blockIdx.y ? off1 : off0;
    int* bsum = blockIdx.y ? bsum1 : bsum0;
    const int n = blockIdx.y ? n1 : n0;

    __shared__ int lds[SCAN_T];
    const int tb = blockIdx.x * (SCAN_T * SCAN_E) + threadIdx.x * SCAN_E;
    int v[SCAN_E];
    int tot = 0;
#pragma unroll
    for (int j = 0; j < SCAN_E; ++j) {
        v[j] = (tb + j < n) ? deg[tb + j] : 0;
        tot += v[j];
    }
    lds[threadIdx.x] = tot;
    __syncthreads();
    for (int s = 1; s < SCAN_T; s <<= 1) {
        int t = (threadIdx.x >= s) ? lds[threadIdx.x - s] : 0;
        __syncthreads();
        lds[threadIdx.x] += t;
        __syncthreads();
    }
    int run = (threadIdx.x > 0) ? lds[threadIdx.x - 1] : 0;
#pragma unroll
    for (int j = 0; j < SCAN_E; ++j) {
        if (tb + j < n) off[tb + j] = run;
        run += v[j];
    }
    if (threadIdx.x == SCAN_T - 1) bsum[blockIdx.x] = lds[SCAN_T - 1];
}
__global__ void scan2_dual_kernel(int* __restrict__ bm, int nbm, int* __restrict__ bu, int nbu) {
    int t = threadIdx.x & 63;
    int* b = (threadIdx.x >= 64) ? bu : bm;
    int nb = (threadIdx.x >= 64) ? nbu : nbm;
    int orig = (t < nb) ? b[t] : 0;
    int v = orig;
    for (int s = 1; s < 64; s <<= 1) {
        int u = __shfl_up(v, s);
        if (t >= s) v += u;
    }
    if (t < nb) b[t] = v - orig;
}
__global__ void scan3_dual_kernel(int* __restrict__ off0, const int* __restrict__ bsum0, int n0,
                                  int* __restrict__ off1, const int* __restrict__ bsum1, int n1) {
    int* off = blockIdx.y ? off1 : off0;
    const int* bsum = blockIdx.y ? bsum1 : bsum0;
    const int n = blockIdx.y ? n1 : n0;
    int i = blockIdx.x * blockDim.x + threadIdx.x;
    if (i < n) off[i] += bsum[i / (SCAN_T * SCAN_E)];
}

__global__ void csr_fill2_kernel(
    const int* __restrict__ esm, const int* __restrict__ edm, const float* __restrict__ eam,
    const int* __restrict__ offm, int* __restrict__ curm, int2* __restrict__ recm,
    const int* __restrict__ esu, const int* __restrict__ edu, const float* __restrict__ eau,
    const int* __restrict__ offu, int* __restrict__ curu, int2* __restrict__ recu, int E)
{
    int e = blockIdx.x * blockDim.x + threadIdx.x;
    if (e < E) {
        int d = edm[e];
        int r = atomicAdd(&curm[d], 1);
        int2 q; q.x = esm[e]; q.y = __float_as_int(eam[e]);
        recm[offm[d] + r] = q;
    } else if (e < 2 * E) {
        e -= E;
        int d = edu[e];
        int r = atomicAdd(&curu[d], 1);
        int2 q; q.x = esu[e]; q.y = __float_as_int(eau[e]);
        recu[offu[d] + r] = q;
    }
}

// ---------------- weight transpose+convert: pre-swizzled K-tile layout ----
// Output layout per matrix: K/32 tiles of [256 x 32] bf16 (8192 ushorts each);
// within a tile, element (c, k=kg*8+e) lives at swz(c,kg)+e — i.e. exactly the
// LDS image the GEMM wants, so global_load_lds can DMA it linearly.
struct TxArgs {
    const float* src[4];
    unsigned short* dst[4];
};
__global__ void txp_kernel(TxArgs a) {
    const int m = blockIdx.y;
    const int K = 256, N = 256;
    const long total = (long)K * N;
    const float* __restrict__ s = a.src[m];
    unsigned short* __restrict__ d = a.dst[m];
    for (long i = (long)blockIdx.x * blockDim.x + threadIdx.x; i < total;
         i += (long)gridDim.x * blockDim.x) {
        int k = (int)(i >> 8), nn = (int)(i & 255);
        int kt = k >> 5, kg = (k >> 3) & 3, e = k & 7;
        d[kt * 8192 + swz(nn, kg) + e] = f2b(s[i]);
    }
}

// ---------------- combine phase-0 + layer-0 weights (pre-swizzled) --------
__global__ void cw_kernel(const float* __restrict__ Wu, const float* __restrict__ bu,
                          const float* __restrict__ Wa, const float* __restrict__ ba,
                          const float* __restrict__ Wb, const float* __restrict__ bb,
                          unsigned short* __restrict__ wt, float* __restrict__ bc)
{
    int tid = blockIdx.x * blockDim.x + threadIdx.x;
    if (tid < 512 * 64) {
        int nn = tid >> 6, k = tid & 63;
        const float* Ws = (nn < 256) ? Wa : Wb;
        int nc = nn & 255;
        float s = 0.f;
        for (int c = 0; c < 64; ++c) s = fmaf(Wu[k * 64 + c], Ws[c * 256 + nc], s);
        int h = nn >> 8, kt = k >> 5, kg = (k >> 3) & 3, e = k & 7;
        wt[h * 16384 + kt * 8192 + swz(nc, kg) + e] = f2b(s);
    } else if (tid < 512 * 64 + 512) {
        int nn = tid - 512 * 64;
        const float* Ws = (nn < 256) ? Wa : Wb;
        const float* bs = (nn < 256) ? ba : bb;
        int nc = nn & 255;
        float s = bs[nc];
        for (int c = 0; c < 64; ++c) s = fmaf(bu[c], Ws[c * 256 + nc], s);
        bc[nn] = s;
    }
}

// ---------------- merged MFMA GEMM, BK=32 (two independent segments) ------
// W tile staged via global_load_lds (16B/lane DMA) from the pre-swizzled
// global image — 4 wave-instructions replace 8 per-thread load/writes.
struct GemmP {
    const void* A; const int* ids;
    const unsigned short* Wt0; const unsigned short* Wt1;
    const float* b0; const float* b1;
    unsigned short* Y0; unsigned short* Y1;
    int n;
};
template<int K, bool GATHER>
__global__ void __launch_bounds__(256) gemm2_kernel(GemmP P0, GemmP P1, int nblk0)
{
    const bool seg1 = (int)blockIdx.x >= nblk0;
    const GemmP P = seg1 ? P1 : P0;
    const int lb = seg1 ? (int)blockIdx.x - nblk0 : (int)blockIdx.x;

    const int t = threadIdx.x;
    const int wid = t >> 6, lane = t & 63;
    const int half = lb & 1;
    const int row0 = (lb >> 1) * 64;
    const unsigned short* Wt = half ? P.Wt1 : P.Wt0;
    const float* bias = half ? P.b1 : P.b0;
    unsigned short* Y = half ? P.Y1 : P.Y0;
    const int n = P.n;

    __shared__ unsigned short SMEM[64 * 32 + 256 * 32];   // As | Ws; reused as C-stage
    unsigned short* As = SMEM;
    unsigned short* Ws = SMEM + 64 * 32;

    f32x4v acc[4][4];
#pragma unroll
    for (int rt = 0; rt < 4; ++rt)
#pragma unroll
        for (int ct = 0; ct < 4; ++ct) acc[rt][ct] = (f32x4v){0.f, 0.f, 0.f, 0.f};

    const int r_st = t >> 2, kg_st = t & 3;
    const int grow = row0 + r_st;
    long abase = 0;
    if (grow < n) abase = GATHER ? (long)P.ids[grow] * K : (long)grow * K;

    // per-wave W staging addresses (uniform LDS base + per-lane global src)
    const char* wsrc0 = (const char*)Wt + (size_t)(wid * 4) * 1024 + (size_t)lane * 16;
    char* wdst0 = (char*)Ws + (size_t)(wid * 4) * 1024;

    for (int kt = 0; kt < K / 32; ++kt) {
        // ---- stage A (register path; swizzled LDS layout) ----
        usht8 av = (usht8)0;
        if (grow < n) {
            if (GATHER) {
                const float* p = (const float*)P.A + abase + kt * 32 + kg_st * 8;
#pragma unroll
                for (int j = 0; j < 8; ++j) av[j] = f2b(p[j]);
            } else {
                av = *(const usht8*)((const unsigned short*)P.A + abase + kt * 32 + kg_st * 8);
            }
        }
        *(usht8*)&As[swz(r_st, kg_st)] = av;
        // ---- stage W: 4 x 1KB DMA per wave from pre-swizzled image ----
        const char* ws = wsrc0 + (size_t)kt * 16384;
#pragma unroll
        for (int it = 0; it < 4; ++it)
            gload16(ws + it * 1024, wdst0 + it * 1024);
        __syncthreads();

        const int kgrp = lane >> 4;
        short8 af[4];
#pragma unroll
        for (int rt = 0; rt < 4; ++rt)
            af[rt] = *(const short8*)&As[swz(rt * 16 + (lane & 15), kgrp)];
#pragma unroll
        for (int ct = 0; ct < 4; ++ct) {
            int col = wid * 64 + ct * 16 + (lane & 15);
            short8 bfr = *(const short8*)&Ws[swz(col, kgrp)];
#pragma unroll
            for (int rt = 0; rt < 4; ++rt)
                acc[rt][ct] = __builtin_amdgcn_mfma_f32_16x16x32_bf16(af[rt], bfr, acc[rt][ct], 0, 0, 0);
        }
        __syncthreads();
    }

    // ---- epilogue: stage bf16 C tile in LDS, store dense 16B chunks ----
    float bb[4];
#pragma unroll
    for (int ct = 0; ct < 4; ++ct) bb[ct] = bias[wid * 64 + ct * 16 + (lane & 15)];

#pragma unroll
    for (int rh = 0; rh < 2; ++rh) {
#pragma unroll
        for (int rt = rh * 2; rt < rh * 2 + 2; ++rt) {
#pragma unroll
            for (int ct = 0; ct < 4; ++ct) {
                int col = wid * 64 + ct * 16 + (lane & 15);
#pragma unroll
                for (int j = 0; j < 4; ++j) {
                    int rl = rt * 16 + (lane >> 4) * 4 + j - rh * 32;
                    SMEM[rl * 256 + col] = f2b(acc[rt][ct][j] + bb[ct]);
                }
            }
        }
        __syncthreads();
#pragma unroll
        for (int i = 0; i < 4; ++i) {
            int idx = t + i * 256;
            int rl = idx >> 5, cseg = (idx & 31) * 8;
            int row = row0 + rh * 32 + rl;
            if (row < n)
                *(usht8*)&Y[(long)row * 256 + cseg] = *(const usht8*)&SMEM[rl * 256 + cseg];
        }
        __syncthreads();
    }
}

// ---------------- merged fused GATv2 layer (two independent segments) -----
// lane = h*16 + q; lane owns channels c = h*64 + q*4 .. +3. One wave per dst
// (per-dst blocks -> HW backfills wave slots). 4-edge batches; scalar f32
// math (proven fastest: 44 VGPR / 46% occupancy); exp2-domain defer-max
// softmax; u32 gather addressing.
// NOTE: segments' read/write buffer sets MUST be disjoint (no launch-internal order).
struct GatP {
    const int* deg; const int* off; const int2* rec;
    const unsigned short* xl; const unsigned short* xr;
    const float* We; const float* att; const float* bias;
    const float* g; const float* be;
    void* y;
    int n;
};
template<bool CONCAT>
__global__ void __launch_bounds__(256) gat2_kernel(GatP P0, GatP P1, int nblk0)
{
    const bool seg1 = (int)blockIdx.x >= nblk0;
    const GatP P = seg1 ? P1 : P0;
    const int lb = seg1 ? (int)blockIdx.x - nblk0 : (int)blockIdx.x;
    const int lane = threadIdx.x & 63;
    const int d = lb * 4 + (threadIdx.x >> 6);
    if (d >= P.n) return;

    const int q = lane & 15;
    const int c0 = ((lane >> 4) << 6) + (q << 2);   // h*64 + q*4
    const unsigned cb = (unsigned)c0 << 1;          // byte offset of lane's channels
    const float LOG2E = 1.4426950408889634f;

    // ---- per-wave constants (logits carried in log2 domain) ----
    float4 We4 = *(const float4*)(P.We + c0);
    float4 att4 = *(const float4*)(P.att + c0);
    float att06[4], att04[4];
#pragma unroll
    for (int i = 0; i < 4; ++i) {
        att06[i] = 0.6f * LOG2E * (&att4.x)[i];
        att04[i] = 0.4f * LOG2E * (&att4.x)[i];
    }
    const int ec = CONCAT ? c0 : (q << 2);
    float4 bi = *(const float4*)(P.bias + ec);
    float4 gg = *(const float4*)(P.g + ec);
    float4 bb = *(const float4*)(P.be + ec);

    us4 xrv = *(const us4*)(P.xr + (long)d * 256 + c0);
    float xr4[4] = {b2f(xrv.x), b2f(xrv.y), b2f(xrv.z), b2f(xrv.w)};

    float m = -1e30f, den = 0.f;
    float acc[4] = {0.f, 0.f, 0.f, 0.f};

    const int dg = P.deg[d], o0 = P.off[d];
    const char* __restrict__ xlb = (const char*)P.xl;

    for (int base = 0; base < dg; base += 64) {
        int2 r;
        if (base + lane < dg) r = P.rec[o0 + base + lane];
        else { r.x = 0; r.y = 0; }
        const int cnt = min(dg - base, 64);
        for (int j = 0; j < cnt; j += 4) {
            us4 xvA[4];
            int aB[4];
#pragma unroll
            for (int u = 0; u < 4; ++u) {
                int s = __builtin_amdgcn_readlane(r.x, j + u);   // SGPR broadcast
                aB[u] = __builtin_amdgcn_readlane(r.y, j + u);
                xvA[u] = *(const us4*)(xlb + (((unsigned)s << 9) + cb));
            }
            float l[4], xvf[4][4];
#pragma unroll
            for (int u = 0; u < 4; ++u) {
                xvf[u][0] = b2f(xvA[u].x); xvf[u][1] = b2f(xvA[u].y);
                xvf[u][2] = b2f(xvA[u].z); xvf[u][3] = b2f(xvA[u].w);
                const float a = __int_as_float(aB[u]);
                float part = 0.f;
#pragma unroll
                for (int i = 0; i < 4; ++i) {
                    float t = xvf[u][i] + fmaf(a, (&We4.x)[i], xr4[i]);
                    part = fmaf(att06[i], t, part);          // log2e*lrelu*att
                    part = fmaf(att04[i], fabsf(t), part);
                }
#pragma unroll
                for (int st = 1; st < 16; st <<= 1) part += __shfl_xor(part, st);
                l[u] = (j + u < cnt) ? part : -1e30f;
            }
            // defer-max rescale (exact): p bounded by 2^11.54 = e^8
            float bmax = fmaxf(fmaxf(l[0], l[1]), fmaxf(l[2], l[3]));
            if (__any(bmax > m + 11.5415603f)) {
                float mn = fmaxf(m, bmax);
                float sc = exp2f(m - mn);
                den *= sc;
#pragma unroll
                for (int i = 0; i < 4; ++i) acc[i] *= sc;
                m = mn;
            }
#pragma unroll
            for (int u = 0; u < 4; ++u) {
                float p = exp2f(l[u] - m);
                den += p;
#pragma unroll
                for (int i = 0; i < 4; ++i) acc[i] = fmaf(p, xvf[u][i], acc[i]);
            }
        }
    }

    const float id = 1.f / (den + 1e-16f);
    if (CONCAT) {
        float v[4], s1 = 0.f, s2 = 0.f;
#pragma unroll
        for (int i = 0; i < 4; ++i) {
            v[i] = fmaf(acc[i], id, (&bi.x)[i]);
            s1 += v[i]; s2 = fmaf(v[i], v[i], s2);
        }
#pragma unroll
        for (int st = 1; st < 64; st <<= 1) {
            s1 += __shfl_xor(s1, st);
            s2 += __shfl_xor(s2, st);
        }
        float mean = s1 * (1.f / 256.f);
        float var = s2 * (1.f / 256.f) - mean * mean;
        float rr = rsqrtf(var + 1e-5f);
        us4 o;
        o.x = f2b(lrelu02(fmaf((&gg.x)[0] * rr, v[0] - mean, (&bb.x)[0])));
        o.y = f2b(lrelu02(fmaf((&gg.x)[1] * rr, v[1] - mean, (&bb.x)[1])));
        o.z = f2b(lrelu02(fmaf((&gg.x)[2] * rr, v[2] - mean, (&bb.x)[2])));
        o.w = f2b(lrelu02(fmaf((&gg.x)[3] * rr, v[3] - mean, (&bb.x)[3])));
        *(us4*)((unsigned short*)P.y + (long)d * 256 + c0) = o;
    } else {
        float vh[4];
#pragma unroll
        for (int i = 0; i < 4; ++i) vh[i] = acc[i] * id;
#pragma unroll
        for (int st = 16; st < 64; st <<= 1)
#pragma unroll
            for (int i = 0; i < 4; ++i) vh[i] += __shfl_xor(vh[i], st);
        float v[4], s1 = 0.f, s2 = 0.f;
#pragma unroll
        for (int i = 0; i < 4; ++i) {
            v[i] = fmaf(0.25f, vh[i], (&bi.x)[i]);
            s1 += v[i]; s2 = fmaf(v[i], v[i], s2);
        }
#pragma unroll
        for (int st = 1; st < 16; st <<= 1) {
            s1 += __shfl_xor(s1, st);
            s2 += __shfl_xor(s2, st);
        }
        float mean = s1 * (1.f / 64.f);
        float var = s2 * (1.f / 64.f) - mean * mean;
        float rr = rsqrtf(var + 1e-5f);
        if (lane < 16) {
            float4 o;
            o.x = lrelu02(fmaf((&gg.x)[0] * rr, v[0] - mean, (&bb.x)[0]));
            o.y = lrelu02(fmaf((&gg.x)[1] * rr, v[1] - mean, (&bb.x)[1]));
            o.z = lrelu02(fmaf((&gg.x)[2] * rr, v[2] - mean, (&bb.x)[2]));
            o.w = lrelu02(fmaf((&gg.x)[3] * rr, v[3] - mean, (&bb.x)[3]));
            *(float4*)((float*)P.y + (long)d * 64 + (q << 2)) = o;
        }
    }
}

// ---------------- host orchestration ----------------
extern "C" void kernel_launch(void* const* d_in, const int* in_sizes, int n_in,
                              void* d_out, int out_size, void* d_ws, size_t ws_size,
                              hipStream_t stream)
{
    auto F = [&](int i) { return (const float*)d_in[i]; };
    auto I = [&](int i) { return (const int*)d_in[i]; };

    const int NU = in_sizes[0];
    const int NM = in_sizes[1];
    const int E  = in_sizes[2] / 2;

    const int* user_ids  = I(0);
    const int* movie_ids = I(1);
    const int* ei_um = I(2);
    const int* ei_mu = I(3);
    const float* ea_um = F(4);
    const float* ea_mu = F(5);
    const float* user_emb  = F(6);
    const float* movie_emb = F(7);
    const float* W_user = F(8),  *b_user = F(9);
    const float* W_movie = F(10), *b_movie = F(11);
    const int L0UM = 12, L0MU = 19, L1UM = 26, L1MU = 33;
    const float* g0u = F(40), *be0u = F(41);
    const float* g0m = F(42), *be0m = F(43);
    const float* g1u = F(44), *be1u = F(45);
    const float* g1m = F(46), *be1m = F(47);

    // ---- workspace layout ----
    char* w = (char*)d_ws;
    size_t off = 0;
    auto alloc = [&](size_t bytes) -> void* {
        void* p = w + off;
        off = (off + bytes + 255) & ~(size_t)255;
        return p;
    };
    bf16* UB1 = (bf16*)alloc((size_t)NU * 256 * 2);
    bf16* UB2 = (bf16*)alloc((size_t)NU * 256 * 2);
    bf16* UB3 = (bf16*)alloc((size_t)NU * 256 * 2);
    bf16* MB1 = (bf16*)alloc((size_t)NM * 256 * 2);
    bf16* MB2 = (bf16*)alloc((size_t)NM * 256 * 2);
    bf16* MB3 = (bf16*)alloc((size_t)NM * 256 * 2);
    int* degcur = (int*)alloc((size_t)2 * (NM + NU) * 4);
    int* deg_m = degcur;
    int* deg_u = degcur + NM;
    int* cur_m = degcur + NM + NU;
    int* cur_u = degcur + 2 * NM + NU;
    int* off_m = (int*)alloc((size_t)NM * 4);
    int* off_u = (int*)alloc((size_t)NU * 4);
    int2* rec_m = (int2*)alloc((size_t)(E + 8) * 8);
    int2* rec_u = (int2*)alloc((size_t)(E + 8) * 8);
    int* bsum_m = (int*)alloc(64 * 4);
    int* bsum_u = (int*)alloc(64 * 4);
    unsigned short* wt_l1um_l = (unsigned short*)alloc(256 * 256 * 2);
    unsigned short* wt_l1mu_r = (unsigned short*)alloc(256 * 256 * 2);
    unsigned short* wt_l1um_r = (unsigned short*)alloc(256 * 256 * 2);
    unsigned short* wt_l1mu_l = (unsigned short*)alloc(256 * 256 * 2);
    unsigned short* wt_c_user  = (unsigned short*)alloc(512 * 64 * 2);
    unsigned short* wt_c_movie = (unsigned short*)alloc(512 * 64 * 2);
    float* bc_user  = (float*)alloc(512 * 4);
    float* bc_movie = (float*)alloc(512 * 4);
    if (off > ws_size) return;

    float* out_u = (float*)d_out;
    float* out_m = out_u + (size_t)NU * 64;

    const int FB = 256;

    // ---- weight prep (pre-swizzled K-tile layout) ----
    TxArgs tx;
    tx.src[0] = F(L1UM+0); tx.dst[0] = wt_l1um_l;
    tx.src[1] = F(L1MU+2); tx.dst[1] = wt_l1mu_r;
    tx.src[2] = F(L1UM+2); tx.dst[2] = wt_l1um_r;
    tx.src[3] = F(L1MU+0); tx.dst[3] = wt_l1mu_l;
    txp_kernel<<<dim3(64, 4), 256, 0, stream>>>(tx);
    cw_kernel<<<CDIV(512 * 64 + 512, 256), 256, 0, stream>>>(
        W_user, b_user, F(L0UM+0), F(L0UM+1), F(L0MU+2), F(L0MU+3), wt_c_user, bc_user);
    cw_kernel<<<CDIV(512 * 64 + 512, 256), 256, 0, stream>>>(
        W_movie, b_movie, F(L0UM+2), F(L0UM+3), F(L0MU+0), F(L0MU+1), wt_c_movie, bc_movie);

    // ---- CSR build (both directions) ----
    fill_i32<<<CDIV(2 * (NM + NU), FB), FB, 0, stream>>>(degcur, 0, (long)2 * (NM + NU));
    hist2_kernel<<<CDIV(2 * E, FB), FB, 0, stream>>>(ei_um + E, ei_mu + E, deg_m, deg_u, E);
    const int nbm = CDIV(NM, SCAN_T * SCAN_E), nbu = CDIV(NU, SCAN_T * SCAN_E);
    scan1_dual_kernel<<<dim3(max(nbm, nbu), 2), SCAN_T, 0, stream>>>(
        deg_m, off_m, bsum_m, NM, deg_u, off_u, bsum_u, NU);
    scan2_dual_kernel<<<1, 128, 0, stream>>>(bsum_m, nbm, bsum_u, nbu);
    scan3_dual_kernel<<<dim3(CDIV(max(NM, NU), FB), 2), FB, 0, stream>>>(
        off_m, bsum_m, NM, off_u, bsum_u, NU);
    csr_fill2_kernel<<<CDIV(2 * E, FB), FB, 0, stream>>>(
        ei_um, ei_um + E, ea_um, off_m, cur_m, rec_m,
        ei_mu, ei_mu + E, ea_mu, off_u, cur_u, rec_u, E);

    // ---- layer-0 projections (merged movie+user; phase-0 folded, K=64) ----
    {
        GemmP PM{movie_emb, movie_ids, wt_c_movie, wt_c_movie + 16384,
                 bc_movie, bc_movie + 256, (unsigned short*)MB1, (unsigned short*)MB3, NM};
        GemmP PU{user_emb, user_ids, wt_c_user, wt_c_user + 16384,
                 bc_user, bc_user + 256, (unsigned short*)UB1, (unsigned short*)UB2, NU};
        int nM = CDIV(NM, 64) * 2, nU = CDIV(NU, 64) * 2;
        gemm2_kernel<64, true><<<nM + nU, 256, 0, stream>>>(PM, PU, nM);
        // MB1=xr_m0, MB3=xl_m0, UB1=xl_u0, UB2=xr_u0
    }

    // ---- layer 0 fused GAT (merged; writes {MB2, UB3} disjoint from reads) ----
    {
        GatP PM{deg_m, off_m, rec_m, (const unsigned short*)UB1, (const unsigned short*)MB1,
                F(L0UM+4), F(L0UM+5), F(L0UM+6), g0m, be0m, MB2, NM};          // xm1
        GatP PU{deg_u, off_u, rec_u, (const unsigned short*)MB3, (const unsigned short*)UB2,
                F(L0MU+4), F(L0MU+5), F(L0MU+6), g0u, be0u, UB3, NU};          // xu1 -> UB3
        gat2_kernel<true><<<CDIV(NM, 4) + CDIV(NU, 4), 256, 0, stream>>>(PM, PU, CDIV(NM, 4));
    }

    // ---- layer-1 projections (merged; reads {MB2,UB3}, writes {MB1,MB3,UB1,UB2}) ----
    {
        GemmP PM{(unsigned short*)MB2, nullptr, wt_l1um_r, wt_l1mu_l,
                 F(L1UM+3), F(L1MU+1), (unsigned short*)MB1, (unsigned short*)MB3, NM};
        GemmP PU{(unsigned short*)UB3, nullptr, wt_l1um_l, wt_l1mu_r,
                 F(L1UM+1), F(L1MU+3), (unsigned short*)UB1, (unsigned short*)UB2, NU};
        int nM = CDIV(NM, 64) * 2, nU = CDIV(NU, 64) * 2;
        gemm2_kernel<256, false><<<nM + nU, 256, 0, stream>>>(PM, PU, nM);
        // MB1=xr_m1, MB3=xl_m1, UB1=xl_u1, UB2=xr_u1
    }

    // ---- layer 1 fused GAT (merged; reads {UB1,MB1,MB3,UB2}, writes d_out) ----
    {
        GatP PM{deg_m, off_m, rec_m, (const unsigned short*)UB1, (const unsigned short*)MB1,
                F(L1UM+4), F(L1UM+5), F(L1UM+6), g1m, be1m, out_m, NM};
        GatP PU{deg_u, off_u, rec_u, (const unsigned short*)MB3, (const unsigned short*)UB2,
                F(L1MU+4), F(L1MU+5), F(L1MU+6), g1u, be1u, out_u, NU};
        gat2_kernel<false><<<CDIV(NM, 4) + CDIV(NU, 4), 256, 0, stream>>>(PM, PU, CDIV(NM, 4));
    }
}